// Round 1
// baseline (4203.574 us; speedup 1.0000x reference)
//
#include <hip/hip_runtime.h>
#include <hip/hip_cooperative_groups.h>
#include <math.h>

namespace cg = cooperative_groups;

#define TT 64
#define HZN 10

__device__ __forceinline__ float sigm(float x) { return 1.f / (1.f + expf(-x)); }
__device__ __forceinline__ float gelu_f(float x) { return 0.5f * x * (1.f + erff(x * 0.70710678118654752f)); }

__device__ __forceinline__ void red32(float (&a)[4][4]) {
#pragma unroll
  for (int q = 0; q < 4; ++q)
#pragma unroll
    for (int r = 0; r < 4; ++r) {
      float v = a[q][r];
      v += __shfl_xor(v, 16); v += __shfl_xor(v, 8); v += __shfl_xor(v, 4);
      v += __shfl_xor(v, 2);  v += __shfl_xor(v, 1);
      a[q][r] = v;
    }
}

__device__ __forceinline__ void red64(float (&a)[4][4]) {
#pragma unroll
  for (int q = 0; q < 4; ++q)
#pragma unroll
    for (int r = 0; r < 4; ++r) {
      float v = a[q][r];
      v += __shfl_xor(v, 32); v += __shfl_xor(v, 16); v += __shfl_xor(v, 8);
      v += __shfl_xor(v, 4);  v += __shfl_xor(v, 2);  v += __shfl_xor(v, 1);
      a[q][r] = v;
    }
}

// ---------------------------------------------------------------- setup: deg/norm + CSR (base graph, 2000 edges, 100 nodes)
__global__ void setup_kernel(const int* __restrict__ ei, const float* __restrict__ ew,
                             int* __restrict__ cptr, int* __restrict__ csrc, float* __restrict__ cnorm) {
  __shared__ float deg[100];
  __shared__ float dinv[100];
  __shared__ int cnt[100];
  __shared__ int pos[100];
  __shared__ int ptr[101];
  const int t = threadIdx.x;
  if (t < 100) { deg[t] = 0.f; cnt[t] = 0; }
  __syncthreads();
  for (int e = t; e < 2000; e += 256) {
    int c = ei[2000 + e];
    atomicAdd(&deg[c], ew[e]);
    atomicAdd(&cnt[c], 1);
  }
  __syncthreads();
  if (t < 100) dinv[t] = (deg[t] > 0.f) ? 1.f / sqrtf(fmaxf(deg[t], 1e-12f)) : 0.f;
  if (t == 0) {
    ptr[0] = 0;
    for (int n = 0; n < 100; ++n) ptr[n + 1] = ptr[n] + cnt[n];
  }
  __syncthreads();
  if (t < 100) pos[t] = ptr[t];
  if (t < 101) cptr[t] = ptr[t];
  __syncthreads();
  for (int e = t; e < 2000; e += 256) {
    int r = ei[e], c = ei[2000 + e];
    int p = atomicAdd(&pos[c], 1);
    csrc[p] = r;
    cnorm[p] = dinv[r] * ew[e] * dinv[c];
  }
}

// ---------------------------------------------------------------- TGConv: scalar gather + gelu expand -> XS[T][B][3200]
__global__ void xs_kernel(const float* __restrict__ win,
                          const int* __restrict__ cptr, const int* __restrict__ csrc,
                          const float* __restrict__ cnorm,
                          const float* __restrict__ tgw, const float* __restrict__ tgv,
                          const float* __restrict__ tgb, const float* __restrict__ Wemb,
                          float* __restrict__ XS) {
  const int g = blockIdx.x * 256 + threadIdx.x;
  if (g >= 102400) return;
  const int n2 = g % 100;      // graph node within copy
  const int base = g - n2;     // copy offset
  float s = 0.f;
  const int p0 = cptr[n2], p1 = cptr[n2 + 1];
  for (int p = p0; p < p1; ++p) s += cnorm[p] * win[base + csrc[p]];
  const float x = win[g];
  const int t = g % 64;
  const int bb = g / 6400;
  const int n = (g / 64) % 100;
  float* dst = XS + (size_t)(t * 16 + bb) * 3200 + n * 32;
  for (int c = 0; c < 32; ++c) {
    float v = s * tgw[c] + x * tgv[c] + tgb[c];
    dst[c] = gelu_f(v) + Wemb[n * 32 + c];
  }
}

// ---------------------------------------------------------------- G0 = XS(1024x3200) @ Wih0(2048x3200)^T + bih0 + bhh0
__global__ __launch_bounds__(256) void g0_gemm(const float* __restrict__ XS, const float* __restrict__ W,
                                               const float* __restrict__ b1, const float* __restrict__ b2,
                                               float* __restrict__ G0) {
  __shared__ float As[16][68];
  __shared__ float Bs[16][68];
  const int tid = threadIdx.x;
  const int m0 = blockIdx.y * 64, n0 = blockIdx.x * 64;
  const int tx = tid & 15, ty = tid >> 4;
  const int lr = tid >> 2, lk = (tid & 3) * 4;
  float acc[4][4] = {};
  for (int k0 = 0; k0 < 3200; k0 += 16) {
    float4 av = *(const float4*)&XS[(size_t)(m0 + lr) * 3200 + k0 + lk];
    float4 bv = *(const float4*)&W[(size_t)(n0 + lr) * 3200 + k0 + lk];
    As[lk + 0][lr] = av.x; As[lk + 1][lr] = av.y; As[lk + 2][lr] = av.z; As[lk + 3][lr] = av.w;
    Bs[lk + 0][lr] = bv.x; Bs[lk + 1][lr] = bv.y; Bs[lk + 2][lr] = bv.z; Bs[lk + 3][lr] = bv.w;
    __syncthreads();
#pragma unroll
    for (int kk = 0; kk < 16; ++kk) {
      float4 a = *(const float4*)&As[kk][ty * 4];
      float4 b = *(const float4*)&Bs[kk][tx * 4];
      acc[0][0] += a.x * b.x; acc[0][1] += a.x * b.y; acc[0][2] += a.x * b.z; acc[0][3] += a.x * b.w;
      acc[1][0] += a.y * b.x; acc[1][1] += a.y * b.y; acc[1][2] += a.y * b.z; acc[1][3] += a.y * b.w;
      acc[2][0] += a.z * b.x; acc[2][1] += a.z * b.y; acc[2][2] += a.z * b.z; acc[2][3] += a.z * b.w;
      acc[3][0] += a.w * b.x; acc[3][1] += a.w * b.y; acc[3][2] += a.w * b.z; acc[3][3] += a.w * b.w;
    }
    __syncthreads();
  }
#pragma unroll
  for (int i = 0; i < 4; ++i) {
    const int m = m0 + ty * 4 + i;
#pragma unroll
    for (int j = 0; j < 4; ++j) {
      const int nn = n0 + tx * 4 + j;
      G0[(size_t)m * 2048 + nn] = acc[i][j] + b1[nn] + b2[nn];
    }
  }
}

// ---------------------------------------------------------------- cooperative: LSTM scans + decoder
struct CoopArgs {
  const float* G0;
  const float* Whh0;
  const float* Wih1; const float* Whh1; const float* bih1; const float* bhh1;
  const float* c1Wih; const float* c1Whh; const float* c1bih; const float* c1bhh;
  const float* c2Wih; const float* c2Whh; const float* c2bih; const float* c2bhh;
  const float* Wp; const float* bp;
  const float* gw; const float* gv; const float* gb;
  const float* Wemb;
  const int* cptr; const int* csrc; const float* cnorm;
  float* hs0; float* hL1; float* c0; float* cL1;
  float* h1d; float* c1b; float* h2d; float* c2b;
  float* pred; float* xin;
  float* out;
};

__global__ __launch_bounds__(512, 2) void coop_kernel(CoopArgs A) {
  cg::grid_group grid = cg::this_grid();
  __shared__ float lds[16384];  // 64 KB
  const int tid = threadIdx.x;
  const int bid = blockIdx.x;
  const int gid = bid * 512 + tid;

  // ---- phase 1: pipelined LSTM0 + LSTM1 scan (65 iterations) ----
  const int layer = bid >> 7;       // 0..1
  const int ublk = bid & 127;       // 0..127 -> 4 units each
  const int u0 = ublk * 4;
  const int bg = tid >> 7;          // batch group of 4
  const int du = (tid >> 5) & 3;    // unit within block
  const int s = tid & 31;           // K-split
  const int n_s = u0 + du;

  for (int t2 = 0; t2 <= TT; ++t2) {
    if (layer == 0) {
      if (t2 < TT) {
        const int t0 = t2;
        float acc[4][4] = {};
        if (t0 > 0) {
          const float4* src = (const float4*)(A.hs0 + (size_t)(t0 - 1) * 8192);
          float4* d4 = (float4*)lds;
          for (int i = tid; i < 2048; i += 512) d4[i] = src[i];
        }
        __syncthreads();
        if (t0 > 0) {
          for (int jj = 0; jj < 16; ++jj) {
            const int j = jj * 32 + s;
            const float w0 = A.Whh0[(n_s) * 512 + j];
            const float w1 = A.Whh0[(512 + n_s) * 512 + j];
            const float w2 = A.Whh0[(1024 + n_s) * 512 + j];
            const float w3 = A.Whh0[(1536 + n_s) * 512 + j];
#pragma unroll
            for (int br = 0; br < 4; ++br) {
              const float hv = lds[(bg * 4 + br) * 512 + j];
              acc[0][br] += w0 * hv; acc[1][br] += w1 * hv;
              acc[2][br] += w2 * hv; acc[3][br] += w3 * hv;
            }
          }
        }
        red32(acc);
        if (s == 0) {
#pragma unroll
          for (int br = 0; br < 4; ++br) {
            const int b = bg * 4 + br;
            const float* g0r = A.G0 + (size_t)(t0 * 16 + b) * 2048;
            const float gi = acc[0][br] + g0r[n_s];
            const float gf = acc[1][br] + g0r[512 + n_s];
            const float gg = acc[2][br] + g0r[1024 + n_s];
            const float go = acc[3][br] + g0r[1536 + n_s];
            const float cp = (t0 > 0) ? A.c0[b * 512 + n_s] : 0.f;
            const float cn = sigm(gf) * cp + sigm(gi) * tanhf(gg);
            const float hn = sigm(go) * tanhf(cn);
            A.c0[b * 512 + n_s] = cn;
            A.hs0[(size_t)t0 * 8192 + b * 512 + n_s] = hn;
          }
        }
      }
    } else {
      if (t2 >= 1) {
        const int t1 = t2 - 1;
        float acc[4][4] = {};
        {
          const float4* sA = (const float4*)(A.hs0 + (size_t)t1 * 8192);
          float4* dA = (float4*)lds;
          for (int i = tid; i < 2048; i += 512) dA[i] = sA[i];
          if (t1 > 0) {
            const float4* sB = (const float4*)(A.hL1 + (t1 & 1) * 8192);
            float4* dB = (float4*)(lds + 8192);
            for (int i = tid; i < 2048; i += 512) dB[i] = sB[i];
          }
        }
        __syncthreads();
        for (int jj = 0; jj < 16; ++jj) {
          const int j = jj * 32 + s;
          const float wa0 = A.Wih1[(n_s) * 512 + j];
          const float wa1 = A.Wih1[(512 + n_s) * 512 + j];
          const float wa2 = A.Wih1[(1024 + n_s) * 512 + j];
          const float wa3 = A.Wih1[(1536 + n_s) * 512 + j];
#pragma unroll
          for (int br = 0; br < 4; ++br) {
            const float ha = lds[(bg * 4 + br) * 512 + j];
            acc[0][br] += wa0 * ha; acc[1][br] += wa1 * ha;
            acc[2][br] += wa2 * ha; acc[3][br] += wa3 * ha;
          }
          if (t1 > 0) {
            const float wb0 = A.Whh1[(n_s) * 512 + j];
            const float wb1 = A.Whh1[(512 + n_s) * 512 + j];
            const float wb2 = A.Whh1[(1024 + n_s) * 512 + j];
            const float wb3 = A.Whh1[(1536 + n_s) * 512 + j];
#pragma unroll
            for (int br = 0; br < 4; ++br) {
              const float hb = lds[8192 + (bg * 4 + br) * 512 + j];
              acc[0][br] += wb0 * hb; acc[1][br] += wb1 * hb;
              acc[2][br] += wb2 * hb; acc[3][br] += wb3 * hb;
            }
          }
        }
        red32(acc);
        if (s == 0) {
#pragma unroll
          for (int br = 0; br < 4; ++br) {
            const int b = bg * 4 + br;
            const float gi = acc[0][br] + A.bih1[n_s] + A.bhh1[n_s];
            const float gf = acc[1][br] + A.bih1[512 + n_s] + A.bhh1[512 + n_s];
            const float gg = acc[2][br] + A.bih1[1024 + n_s] + A.bhh1[1024 + n_s];
            const float go = acc[3][br] + A.bih1[1536 + n_s] + A.bhh1[1536 + n_s];
            const float cp = (t1 > 0) ? A.cL1[b * 512 + n_s] : 0.f;
            const float cn = sigm(gf) * cp + sigm(gi) * tanhf(gg);
            const float hn = sigm(go) * tanhf(cn);
            A.cL1[b * 512 + n_s] = cn;
            A.hL1[((t1 & 1) ^ 1) * 8192 + b * 512 + n_s] = hn;
          }
        }
      }
    }
    grid.sync();
  }

  // ---- seed decoder state: h1=c1=hs0[63], h2=c2=hL1(final, buffer 0) ----
  if (gid < 8192) {
    const float h1v = A.hs0[(size_t)63 * 8192 + gid];
    A.h1d[gid] = h1v; A.c1b[gid] = h1v;
    const float h2v = A.hL1[gid];
    A.h2d[gid] = h2v; A.c2b[gid] = h2v;
  }
  grid.sync();

  // ---- decoder: 10 horizon steps ----
  for (int hz = 0; hz < HZN; ++hz) {
    const int cur = hz & 1, nxt = cur ^ 1;

    // P: pred = h2 @ Wp^T + bp ; write output
    if (gid < 25600) {
      const int bn = gid >> 4, sp = gid & 15;
      const int b = bn / 100, n = bn % 100;
      const float* h2 = A.h2d + cur * 8192 + b * 512;
      const float* wp = A.Wp + n * 512;
      float a = 0.f;
      for (int jj = 0; jj < 32; ++jj) { const int j = jj * 16 + sp; a += h2[j] * wp[j]; }
      a += __shfl_xor(a, 1); a += __shfl_xor(a, 2); a += __shfl_xor(a, 4); a += __shfl_xor(a, 8);
      if (sp == 0) {
        const float v = a + A.bp[n];
        A.pred[bn] = v;
        A.out[bn * HZN + hz] = v;
      }
    }
    grid.sync();

    // X: graph conv on pred -> xin
    if (gid < 51200) {
      const int b = gid / 3200, rem = gid % 3200;
      const int n = rem >> 5, c = rem & 31;
      float s2 = 0.f;
      const int p0 = A.cptr[n], p1 = A.cptr[n + 1];
      for (int p = p0; p < p1; ++p) s2 += A.cnorm[p] * A.pred[b * 100 + A.csrc[p]];
      const float pv = A.pred[b * 100 + n];
      const float v = s2 * A.gw[c] + pv * A.gv[c] + A.gb[c];
      A.xin[gid] = gelu_f(v) + A.Wemb[n * 32 + c];
    }
    grid.sync();

    // G1: cell1 gates (K = 3200 xin + 512 h1) + update
    {
      const int uc = bid & 63, bq = bid >> 6;
      const int u = tid >> 6, sl = tid & 63;
      const int n = uc * 8 + u;
      float* xinl = lds;           // 4*3200
      float* h1l = lds + 12800;    // 4*512
      {
        const float4* xs4 = (const float4*)(A.xin + (size_t)bq * 4 * 3200);
        float4* xd = (float4*)xinl;
        for (int i = tid; i < 3200; i += 512) xd[i] = xs4[i];
        ((float4*)h1l)[tid] = ((const float4*)(A.h1d + cur * 8192 + bq * 2048))[tid];
      }
      __syncthreads();
      float acc[4][4] = {};
      for (int jj = 0; jj < 50; ++jj) {
        const int j = jj * 64 + sl;
        const float w0 = A.c1Wih[(size_t)(n) * 3200 + j];
        const float w1 = A.c1Wih[(size_t)(512 + n) * 3200 + j];
        const float w2 = A.c1Wih[(size_t)(1024 + n) * 3200 + j];
        const float w3 = A.c1Wih[(size_t)(1536 + n) * 3200 + j];
#pragma unroll
        for (int bl = 0; bl < 4; ++bl) {
          const float xv = xinl[bl * 3200 + j];
          acc[0][bl] += w0 * xv; acc[1][bl] += w1 * xv;
          acc[2][bl] += w2 * xv; acc[3][bl] += w3 * xv;
        }
      }
      for (int jj = 0; jj < 8; ++jj) {
        const int j = jj * 64 + sl;
        const float w0 = A.c1Whh[(n) * 512 + j];
        const float w1 = A.c1Whh[(512 + n) * 512 + j];
        const float w2 = A.c1Whh[(1024 + n) * 512 + j];
        const float w3 = A.c1Whh[(1536 + n) * 512 + j];
#pragma unroll
        for (int bl = 0; bl < 4; ++bl) {
          const float hv = h1l[bl * 512 + j];
          acc[0][bl] += w0 * hv; acc[1][bl] += w1 * hv;
          acc[2][bl] += w2 * hv; acc[3][bl] += w3 * hv;
        }
      }
      red64(acc);
      if (sl == 0) {
#pragma unroll
        for (int bl = 0; bl < 4; ++bl) {
          const int b = bq * 4 + bl;
          const float gi = acc[0][bl] + A.c1bih[n] + A.c1bhh[n];
          const float gf = acc[1][bl] + A.c1bih[512 + n] + A.c1bhh[512 + n];
          const float gg = acc[2][bl] + A.c1bih[1024 + n] + A.c1bhh[1024 + n];
          const float go = acc[3][bl] + A.c1bih[1536 + n] + A.c1bhh[1536 + n];
          const float cp = A.c1b[b * 512 + n];
          const float cn = sigm(gf) * cp + sigm(gi) * tanhf(gg);
          const float hn = sigm(go) * tanhf(cn);
          A.c1b[b * 512 + n] = cn;
          A.h1d[nxt * 8192 + b * 512 + n] = hn;
        }
      }
    }
    grid.sync();

    // G2: cell2 gates (K = 512 h1new + 512 h2) + update
    {
      const int uc = bid & 63, bq = bid >> 6;
      const int u = tid >> 6, sl = tid & 63;
      const int n = uc * 8 + u;
      float* hAl = lds;
      float* hBl = lds + 2048;
      ((float4*)hAl)[tid] = ((const float4*)(A.h1d + nxt * 8192 + bq * 2048))[tid];
      ((float4*)hBl)[tid] = ((const float4*)(A.h2d + cur * 8192 + bq * 2048))[tid];
      __syncthreads();
      float acc[4][4] = {};
      for (int jj = 0; jj < 8; ++jj) {
        const int j = jj * 64 + sl;
        const float wa0 = A.c2Wih[(n) * 512 + j];
        const float wa1 = A.c2Wih[(512 + n) * 512 + j];
        const float wa2 = A.c2Wih[(1024 + n) * 512 + j];
        const float wa3 = A.c2Wih[(1536 + n) * 512 + j];
        const float wb0 = A.c2Whh[(n) * 512 + j];
        const float wb1 = A.c2Whh[(512 + n) * 512 + j];
        const float wb2 = A.c2Whh[(1024 + n) * 512 + j];
        const float wb3 = A.c2Whh[(1536 + n) * 512 + j];
#pragma unroll
        for (int bl = 0; bl < 4; ++bl) {
          const float ha = hAl[bl * 512 + j];
          const float hb = hBl[bl * 512 + j];
          acc[0][bl] += wa0 * ha + wb0 * hb;
          acc[1][bl] += wa1 * ha + wb1 * hb;
          acc[2][bl] += wa2 * ha + wb2 * hb;
          acc[3][bl] += wa3 * ha + wb3 * hb;
        }
      }
      red64(acc);
      if (sl == 0) {
#pragma unroll
        for (int bl = 0; bl < 4; ++bl) {
          const int b = bq * 4 + bl;
          const float gi = acc[0][bl] + A.c2bih[n] + A.c2bhh[n];
          const float gf = acc[1][bl] + A.c2bih[512 + n] + A.c2bhh[512 + n];
          const float gg = acc[2][bl] + A.c2bih[1024 + n] + A.c2bhh[1024 + n];
          const float go = acc[3][bl] + A.c2bih[1536 + n] + A.c2bhh[1536 + n];
          const float cp = A.c2b[b * 512 + n];
          const float cn = sigm(gf) * cp + sigm(gi) * tanhf(gg);
          const float hn = sigm(go) * tanhf(cn);
          A.c2b[b * 512 + n] = cn;
          A.h2d[nxt * 8192 + b * 512 + n] = hn;
        }
      }
    }
    grid.sync();
  }
}

// ---------------------------------------------------------------- launch
extern "C" void kernel_launch(void* const* d_in, const int* in_sizes, int n_in,
                              void* d_out, int out_size, void* d_ws, size_t ws_size,
                              hipStream_t stream) {
  (void)in_sizes; (void)n_in; (void)out_size; (void)ws_size;
  const float* window = (const float*)d_in[0];
  const int* ei = (const int*)d_in[1];
  const float* ew = (const float*)d_in[2];
  const float* Wemb = (const float*)d_in[3];
  const float* tgw = (const float*)d_in[4];
  const float* tgv = (const float*)d_in[5];
  const float* tgb = (const float*)d_in[6];
  const float* gw = (const float*)d_in[7];
  const float* gv = (const float*)d_in[8];
  const float* gb = (const float*)d_in[9];
  const float* Wih0 = (const float*)d_in[10];
  const float* Whh0 = (const float*)d_in[11];
  const float* bih0 = (const float*)d_in[12];
  const float* bhh0 = (const float*)d_in[13];
  const float* Wih1 = (const float*)d_in[14];
  const float* Whh1 = (const float*)d_in[15];
  const float* bih1 = (const float*)d_in[16];
  const float* bhh1 = (const float*)d_in[17];
  const float* c1Wih = (const float*)d_in[18];
  const float* c1Whh = (const float*)d_in[19];
  const float* c1bih = (const float*)d_in[20];
  const float* c1bhh = (const float*)d_in[21];
  const float* c2Wih = (const float*)d_in[22];
  const float* c2Whh = (const float*)d_in[23];
  const float* c2bih = (const float*)d_in[24];
  const float* c2bhh = (const float*)d_in[25];
  const float* Wp = (const float*)d_in[26];
  const float* bp = (const float*)d_in[27];

  char* w = (char*)d_ws;
  size_t off = 0;
  auto alloc = [&](size_t bytes) { void* p = w + off; off = (off + bytes + 255) & ~(size_t)255; return p; };
  int* cptr = (int*)alloc(101 * 4);
  int* csrc = (int*)alloc(2000 * 4);
  float* cnorm = (float*)alloc(2000 * 4);
  float* XS = (float*)alloc((size_t)1024 * 3200 * 4);
  float* G0 = (float*)alloc((size_t)1024 * 2048 * 4);
  float* hs0 = (float*)alloc((size_t)64 * 8192 * 4);
  float* hL1 = (float*)alloc((size_t)2 * 8192 * 4);
  float* c0 = (float*)alloc((size_t)8192 * 4);
  float* cL1 = (float*)alloc((size_t)8192 * 4);
  float* h1d = (float*)alloc((size_t)2 * 8192 * 4);
  float* c1b = (float*)alloc((size_t)8192 * 4);
  float* h2d = (float*)alloc((size_t)2 * 8192 * 4);
  float* c2b = (float*)alloc((size_t)8192 * 4);
  float* pred = (float*)alloc(1600 * 4);
  float* xin = (float*)alloc((size_t)51200 * 4);

  setup_kernel<<<1, 256, 0, stream>>>(ei, ew, cptr, csrc, cnorm);
  xs_kernel<<<400, 256, 0, stream>>>(window, cptr, csrc, cnorm, tgw, tgv, tgb, Wemb, XS);
  g0_gemm<<<dim3(32, 16), 256, 0, stream>>>(XS, Wih0, bih0, bhh0, G0);

  CoopArgs A;
  A.G0 = G0; A.Whh0 = Whh0;
  A.Wih1 = Wih1; A.Whh1 = Whh1; A.bih1 = bih1; A.bhh1 = bhh1;
  A.c1Wih = c1Wih; A.c1Whh = c1Whh; A.c1bih = c1bih; A.c1bhh = c1bhh;
  A.c2Wih = c2Wih; A.c2Whh = c2Whh; A.c2bih = c2bih; A.c2bhh = c2bhh;
  A.Wp = Wp; A.bp = bp; A.gw = gw; A.gv = gv; A.gb = gb; A.Wemb = Wemb;
  A.cptr = cptr; A.csrc = csrc; A.cnorm = cnorm;
  A.hs0 = hs0; A.hL1 = hL1; A.c0 = c0; A.cL1 = cL1;
  A.h1d = h1d; A.c1b = c1b; A.h2d = h2d; A.c2b = c2b;
  A.pred = pred; A.xin = xin;
  A.out = (float*)d_out;
  void* params[] = { &A };
  hipLaunchCooperativeKernel(coop_kernel, dim3(256), dim3(512), params, 0, stream);
}

// Round 2
// 1899.973 us; speedup vs baseline: 2.2124x; 2.2124x over previous
//
#include <hip/hip_runtime.h>
#include <math.h>

#define TT 64
#define HZN 10
#define NBLK 256

__device__ __forceinline__ float sigm(float x) { return 1.f / (1.f + expf(-x)); }
__device__ __forceinline__ float gelu_f(float x) { return 0.5f * x * (1.f + erff(x * 0.70710678118654752f)); }

// agent-scope coherent accessors: bypass the (non-coherent) per-XCD L2 for
// cross-block data, so the barrier never needs a full L2 flush.
__device__ __forceinline__ float cLd(const float* p) {
  return __hip_atomic_load(p, __ATOMIC_RELAXED, __HIP_MEMORY_SCOPE_AGENT);
}
__device__ __forceinline__ void cSt(float* p, float v) {
  __hip_atomic_store(p, v, __ATOMIC_RELAXED, __HIP_MEMORY_SCOPE_AGENT);
}

// flag-based grid barrier, no L2 flush. flags[bid] & *gen zeroed before launch.
__device__ __forceinline__ void gbar(unsigned* flags, unsigned* gen,
                                     int bid, int tid, unsigned& bgen) {
  ++bgen;
  __syncthreads();  // compiler drains vmcnt per wave before s_barrier
  if (bid == 0) {
    if (tid > 0 && tid < NBLK) {
      while (__hip_atomic_load(&flags[tid], __ATOMIC_RELAXED, __HIP_MEMORY_SCOPE_AGENT) < bgen)
        __builtin_amdgcn_s_sleep(1);
    }
    __syncthreads();
    if (tid == 0)
      __hip_atomic_store(gen, bgen, __ATOMIC_RELAXED, __HIP_MEMORY_SCOPE_AGENT);
  } else {
    if (tid == 0) {
      asm volatile("s_waitcnt vmcnt(0)" ::: "memory");
      __hip_atomic_store(&flags[bid], bgen, __ATOMIC_RELAXED, __HIP_MEMORY_SCOPE_AGENT);
      while (__hip_atomic_load(gen, __ATOMIC_RELAXED, __HIP_MEMORY_SCOPE_AGENT) < bgen)
        __builtin_amdgcn_s_sleep(1);
    }
    __syncthreads();
  }
}

__device__ __forceinline__ void red32(float (&a)[4][4]) {
#pragma unroll
  for (int q = 0; q < 4; ++q)
#pragma unroll
    for (int r = 0; r < 4; ++r) {
      float v = a[q][r];
      v += __shfl_xor(v, 16); v += __shfl_xor(v, 8); v += __shfl_xor(v, 4);
      v += __shfl_xor(v, 2);  v += __shfl_xor(v, 1);
      a[q][r] = v;
    }
}

__device__ __forceinline__ void red64(float (&a)[4][4]) {
#pragma unroll
  for (int q = 0; q < 4; ++q)
#pragma unroll
    for (int r = 0; r < 4; ++r) {
      float v = a[q][r];
      v += __shfl_xor(v, 32); v += __shfl_xor(v, 16); v += __shfl_xor(v, 8);
      v += __shfl_xor(v, 4);  v += __shfl_xor(v, 2);  v += __shfl_xor(v, 1);
      a[q][r] = v;
    }
}

// ---------------------------------------------------------------- setup
__global__ void setup_kernel(const int* __restrict__ ei, const float* __restrict__ ew,
                             int* __restrict__ cptr, int* __restrict__ csrc, float* __restrict__ cnorm) {
  __shared__ float deg[100];
  __shared__ float dinv[100];
  __shared__ int cnt[100];
  __shared__ int pos[100];
  __shared__ int ptr[101];
  const int t = threadIdx.x;
  if (t < 100) { deg[t] = 0.f; cnt[t] = 0; }
  __syncthreads();
  for (int e = t; e < 2000; e += 256) {
    int c = ei[2000 + e];
    atomicAdd(&deg[c], ew[e]);
    atomicAdd(&cnt[c], 1);
  }
  __syncthreads();
  if (t < 100) dinv[t] = (deg[t] > 0.f) ? 1.f / sqrtf(fmaxf(deg[t], 1e-12f)) : 0.f;
  if (t == 0) {
    ptr[0] = 0;
    for (int n = 0; n < 100; ++n) ptr[n + 1] = ptr[n] + cnt[n];
  }
  __syncthreads();
  if (t < 100) pos[t] = ptr[t];
  if (t < 101) cptr[t] = ptr[t];
  __syncthreads();
  for (int e = t; e < 2000; e += 256) {
    int r = ei[e], c = ei[2000 + e];
    int p = atomicAdd(&pos[c], 1);
    csrc[p] = r;
    cnorm[p] = dinv[r] * ew[e] * dinv[c];
  }
}

// ---------------------------------------------------------------- TGConv -> XS[T][B][3200]
__global__ void xs_kernel(const float* __restrict__ win,
                          const int* __restrict__ cptr, const int* __restrict__ csrc,
                          const float* __restrict__ cnorm,
                          const float* __restrict__ tgw, const float* __restrict__ tgv,
                          const float* __restrict__ tgb, const float* __restrict__ Wemb,
                          float* __restrict__ XS) {
  const int g = blockIdx.x * 256 + threadIdx.x;
  if (g >= 102400) return;
  const int n2 = g % 100;
  const int base = g - n2;
  float s = 0.f;
  const int p0 = cptr[n2], p1 = cptr[n2 + 1];
  for (int p = p0; p < p1; ++p) s += cnorm[p] * win[base + csrc[p]];
  const float x = win[g];
  const int t = g % 64;
  const int bb = g / 6400;
  const int n = (g / 64) % 100;
  float* dst = XS + (size_t)(t * 16 + bb) * 3200 + n * 32;
  for (int c = 0; c < 32; ++c) {
    float v = s * tgw[c] + x * tgv[c] + tgb[c];
    dst[c] = gelu_f(v) + Wemb[n * 32 + c];
  }
}

// ---------------------------------------------------------------- G0 = XS @ Wih0^T + biases
__global__ __launch_bounds__(256) void g0_gemm(const float* __restrict__ XS, const float* __restrict__ W,
                                               const float* __restrict__ b1, const float* __restrict__ b2,
                                               float* __restrict__ G0) {
  __shared__ float As[16][68];
  __shared__ float Bs[16][68];
  const int tid = threadIdx.x;
  const int m0 = blockIdx.y * 64, n0 = blockIdx.x * 64;
  const int tx = tid & 15, ty = tid >> 4;
  const int lr = tid >> 2, lk = (tid & 3) * 4;
  float acc[4][4] = {};
  for (int k0 = 0; k0 < 3200; k0 += 16) {
    float4 av = *(const float4*)&XS[(size_t)(m0 + lr) * 3200 + k0 + lk];
    float4 bv = *(const float4*)&W[(size_t)(n0 + lr) * 3200 + k0 + lk];
    As[lk + 0][lr] = av.x; As[lk + 1][lr] = av.y; As[lk + 2][lr] = av.z; As[lk + 3][lr] = av.w;
    Bs[lk + 0][lr] = bv.x; Bs[lk + 1][lr] = bv.y; Bs[lk + 2][lr] = bv.z; Bs[lk + 3][lr] = bv.w;
    __syncthreads();
#pragma unroll
    for (int kk = 0; kk < 16; ++kk) {
      float4 a = *(const float4*)&As[kk][ty * 4];
      float4 b = *(const float4*)&Bs[kk][tx * 4];
      acc[0][0] += a.x * b.x; acc[0][1] += a.x * b.y; acc[0][2] += a.x * b.z; acc[0][3] += a.x * b.w;
      acc[1][0] += a.y * b.x; acc[1][1] += a.y * b.y; acc[1][2] += a.y * b.z; acc[1][3] += a.y * b.w;
      acc[2][0] += a.z * b.x; acc[2][1] += a.z * b.y; acc[2][2] += a.z * b.z; acc[2][3] += a.z * b.w;
      acc[3][0] += a.w * b.x; acc[3][1] += a.w * b.y; acc[3][2] += a.w * b.z; acc[3][3] += a.w * b.w;
    }
    __syncthreads();
  }
#pragma unroll
  for (int i = 0; i < 4; ++i) {
    const int m = m0 + ty * 4 + i;
#pragma unroll
    for (int j = 0; j < 4; ++j) {
      const int nn = n0 + tx * 4 + j;
      G0[(size_t)m * 2048 + nn] = acc[i][j] + b1[nn] + b2[nn];
    }
  }
}

// ---------------------------------------------------------------- cooperative: LSTM scans + decoder
struct CoopArgs {
  const float* G0;
  const float* Whh0;
  const float* Wih1; const float* Whh1; const float* bih1; const float* bhh1;
  const float* c1Wih; const float* c1Whh; const float* c1bih; const float* c1bhh;
  const float* c2Wih; const float* c2Whh; const float* c2bih; const float* c2bhh;
  const float* Wp; const float* bp;
  const float* gw; const float* gv; const float* gb;
  const float* Wemb;
  const int* cptr; const int* csrc; const float* cnorm;
  float* hs0; float* hL1; float* c0; float* cL1;
  float* h1d; float* c1b; float* h2d; float* c2b;
  float* pred; float* xin;
  unsigned* flags; unsigned* gen;
  float* out;
};

__global__ __launch_bounds__(512, 2) void coop_kernel(CoopArgs A) {
  __shared__ float lds[16384];  // 64 KB
  const int tid = threadIdx.x;
  const int bid = blockIdx.x;
  const int gid = bid * 512 + tid;
  unsigned bgen = 0;

  // ---- phase 1: pipelined LSTM0 + LSTM1 scan (65 iterations) ----
  const int layer = bid >> 7;
  const int ublk = bid & 127;
  const int u0 = ublk * 4;
  const int bg = tid >> 7;
  const int du = (tid >> 5) & 3;
  const int s = tid & 31;
  const int n_s = u0 + du;

  for (int t2 = 0; t2 <= TT; ++t2) {
    if (layer == 0) {
      if (t2 < TT) {
        const int t0 = t2;
        float acc[4][4] = {};
        if (t0 > 0) {
          const float* src = A.hs0 + (size_t)(t0 - 1) * 8192;
          for (int i = tid; i < 8192; i += 512) lds[i] = cLd(&src[i]);
        }
        __syncthreads();
        if (t0 > 0) {
          for (int jj = 0; jj < 16; ++jj) {
            const int j = jj * 32 + s;
            const float w0 = A.Whh0[(n_s) * 512 + j];
            const float w1 = A.Whh0[(512 + n_s) * 512 + j];
            const float w2 = A.Whh0[(1024 + n_s) * 512 + j];
            const float w3 = A.Whh0[(1536 + n_s) * 512 + j];
#pragma unroll
            for (int br = 0; br < 4; ++br) {
              const float hv = lds[(bg * 4 + br) * 512 + j];
              acc[0][br] += w0 * hv; acc[1][br] += w1 * hv;
              acc[2][br] += w2 * hv; acc[3][br] += w3 * hv;
            }
          }
        }
        red32(acc);
        if (s == 0) {
#pragma unroll
          for (int br = 0; br < 4; ++br) {
            const int b = bg * 4 + br;
            const float* g0r = A.G0 + (size_t)(t0 * 16 + b) * 2048;
            const float gi = acc[0][br] + g0r[n_s];
            const float gf = acc[1][br] + g0r[512 + n_s];
            const float gg = acc[2][br] + g0r[1024 + n_s];
            const float go = acc[3][br] + g0r[1536 + n_s];
            const float cp = (t0 > 0) ? A.c0[b * 512 + n_s] : 0.f;
            const float cn = sigm(gf) * cp + sigm(gi) * tanhf(gg);
            const float hn = sigm(go) * tanhf(cn);
            A.c0[b * 512 + n_s] = cn;
            cSt(&A.hs0[(size_t)t0 * 8192 + b * 512 + n_s], hn);
          }
        }
      }
    } else {
      if (t2 >= 1) {
        const int t1 = t2 - 1;
        float acc[4][4] = {};
        {
          const float* sA = A.hs0 + (size_t)t1 * 8192;
          for (int i = tid; i < 8192; i += 512) lds[i] = cLd(&sA[i]);
          if (t1 > 0) {
            const float* sB = A.hL1 + (t1 & 1) * 8192;
            for (int i = tid; i < 8192; i += 512) lds[8192 + i] = cLd(&sB[i]);
          }
        }
        __syncthreads();
        for (int jj = 0; jj < 16; ++jj) {
          const int j = jj * 32 + s;
          const float wa0 = A.Wih1[(n_s) * 512 + j];
          const float wa1 = A.Wih1[(512 + n_s) * 512 + j];
          const float wa2 = A.Wih1[(1024 + n_s) * 512 + j];
          const float wa3 = A.Wih1[(1536 + n_s) * 512 + j];
#pragma unroll
          for (int br = 0; br < 4; ++br) {
            const float ha = lds[(bg * 4 + br) * 512 + j];
            acc[0][br] += wa0 * ha; acc[1][br] += wa1 * ha;
            acc[2][br] += wa2 * ha; acc[3][br] += wa3 * ha;
          }
          if (t1 > 0) {
            const float wb0 = A.Whh1[(n_s) * 512 + j];
            const float wb1 = A.Whh1[(512 + n_s) * 512 + j];
            const float wb2 = A.Whh1[(1024 + n_s) * 512 + j];
            const float wb3 = A.Whh1[(1536 + n_s) * 512 + j];
#pragma unroll
            for (int br = 0; br < 4; ++br) {
              const float hb = lds[8192 + (bg * 4 + br) * 512 + j];
              acc[0][br] += wb0 * hb; acc[1][br] += wb1 * hb;
              acc[2][br] += wb2 * hb; acc[3][br] += wb3 * hb;
            }
          }
        }
        red32(acc);
        if (s == 0) {
#pragma unroll
          for (int br = 0; br < 4; ++br) {
            const int b = bg * 4 + br;
            const float gi = acc[0][br] + A.bih1[n_s] + A.bhh1[n_s];
            const float gf = acc[1][br] + A.bih1[512 + n_s] + A.bhh1[512 + n_s];
            const float gg = acc[2][br] + A.bih1[1024 + n_s] + A.bhh1[1024 + n_s];
            const float go = acc[3][br] + A.bih1[1536 + n_s] + A.bhh1[1536 + n_s];
            const float cp = (t1 > 0) ? A.cL1[b * 512 + n_s] : 0.f;
            const float cn = sigm(gf) * cp + sigm(gi) * tanhf(gg);
            const float hn = sigm(go) * tanhf(cn);
            A.cL1[b * 512 + n_s] = cn;
            cSt(&A.hL1[((t1 & 1) ^ 1) * 8192 + b * 512 + n_s], hn);
          }
        }
      }
    }
    gbar(A.flags, A.gen, bid, tid, bgen);
  }

  // ---- seed decoder state ----
  if (gid < 8192) {
    const float h1v = cLd(&A.hs0[(size_t)63 * 8192 + gid]);
    cSt(&A.h1d[gid], h1v); cSt(&A.c1b[gid], h1v);
    const float h2v = cLd(&A.hL1[gid]);
    cSt(&A.h2d[gid], h2v); cSt(&A.c2b[gid], h2v);
  }
  gbar(A.flags, A.gen, bid, tid, bgen);

  // ---- decoder: 10 horizon steps ----
  for (int hz = 0; hz < HZN; ++hz) {
    const int cur = hz & 1, nxt = cur ^ 1;

    // P: pred = h2 @ Wp^T + bp
    if (gid < 25600) {
      const int bn = gid >> 4, sp = gid & 15;
      const int b = bn / 100, n = bn % 100;
      const float* h2 = A.h2d + cur * 8192 + b * 512;
      const float* wp = A.Wp + n * 512;
      float a = 0.f;
      for (int jj = 0; jj < 32; ++jj) { const int j = jj * 16 + sp; a += cLd(&h2[j]) * wp[j]; }
      a += __shfl_xor(a, 1); a += __shfl_xor(a, 2); a += __shfl_xor(a, 4); a += __shfl_xor(a, 8);
      if (sp == 0) {
        const float v = a + A.bp[n];
        cSt(&A.pred[bn], v);
        A.out[bn * HZN + hz] = v;
      }
    }
    gbar(A.flags, A.gen, bid, tid, bgen);

    // X: graph conv on pred -> xin  (stage pred in LDS)
    if (bid < 100) {
      for (int i = tid; i < 1600; i += 512) lds[i] = cLd(&A.pred[i]);
      __syncthreads();
      const int g2 = bid * 512 + tid;
      const int b = g2 / 3200, rem = g2 % 3200;
      const int n = rem >> 5, c = rem & 31;
      float s2 = 0.f;
      const int p0 = A.cptr[n], p1 = A.cptr[n + 1];
      for (int p = p0; p < p1; ++p) s2 += A.cnorm[p] * lds[b * 100 + A.csrc[p]];
      const float pv = lds[b * 100 + n];
      const float v = s2 * A.gw[c] + pv * A.gv[c] + A.gb[c];
      cSt(&A.xin[g2], gelu_f(v) + A.Wemb[n * 32 + c]);
    }
    gbar(A.flags, A.gen, bid, tid, bgen);

    // G1: cell1 gates (K = 3200 xin + 512 h1) + update
    {
      const int uc = bid & 63, bq = bid >> 6;
      const int u = tid >> 6, sl = tid & 63;
      const int n = uc * 8 + u;
      float* xinl = lds;           // 4*3200
      float* h1l = lds + 12800;    // 4*512
      for (int i = tid; i < 12800; i += 512) xinl[i] = cLd(&A.xin[(size_t)bq * 12800 + i]);
      for (int i = tid; i < 2048; i += 512) h1l[i] = cLd(&A.h1d[cur * 8192 + bq * 2048 + i]);
      __syncthreads();
      float acc[4][4] = {};
      for (int jj = 0; jj < 50; ++jj) {
        const int j = jj * 64 + sl;
        const float w0 = A.c1Wih[(size_t)(n) * 3200 + j];
        const float w1 = A.c1Wih[(size_t)(512 + n) * 3200 + j];
        const float w2 = A.c1Wih[(size_t)(1024 + n) * 3200 + j];
        const float w3 = A.c1Wih[(size_t)(1536 + n) * 3200 + j];
#pragma unroll
        for (int bl = 0; bl < 4; ++bl) {
          const float xv = xinl[bl * 3200 + j];
          acc[0][bl] += w0 * xv; acc[1][bl] += w1 * xv;
          acc[2][bl] += w2 * xv; acc[3][bl] += w3 * xv;
        }
      }
      for (int jj = 0; jj < 8; ++jj) {
        const int j = jj * 64 + sl;
        const float w0 = A.c1Whh[(n) * 512 + j];
        const float w1 = A.c1Whh[(512 + n) * 512 + j];
        const float w2 = A.c1Whh[(1024 + n) * 512 + j];
        const float w3 = A.c1Whh[(1536 + n) * 512 + j];
#pragma unroll
        for (int bl = 0; bl < 4; ++bl) {
          const float hv = h1l[bl * 512 + j];
          acc[0][bl] += w0 * hv; acc[1][bl] += w1 * hv;
          acc[2][bl] += w2 * hv; acc[3][bl] += w3 * hv;
        }
      }
      red64(acc);
      if (sl == 0) {
#pragma unroll
        for (int bl = 0; bl < 4; ++bl) {
          const int b = bq * 4 + bl;
          const float gi = acc[0][bl] + A.c1bih[n] + A.c1bhh[n];
          const float gf = acc[1][bl] + A.c1bih[512 + n] + A.c1bhh[512 + n];
          const float gg = acc[2][bl] + A.c1bih[1024 + n] + A.c1bhh[1024 + n];
          const float go = acc[3][bl] + A.c1bih[1536 + n] + A.c1bhh[1536 + n];
          const float cp = cLd(&A.c1b[b * 512 + n]);
          const float cn = sigm(gf) * cp + sigm(gi) * tanhf(gg);
          const float hn = sigm(go) * tanhf(cn);
          cSt(&A.c1b[b * 512 + n], cn);
          cSt(&A.h1d[nxt * 8192 + b * 512 + n], hn);
        }
      }
    }
    gbar(A.flags, A.gen, bid, tid, bgen);

    // G2: cell2 gates (K = 512 h1new + 512 h2) + update
    {
      const int uc = bid & 63, bq = bid >> 6;
      const int u = tid >> 6, sl = tid & 63;
      const int n = uc * 8 + u;
      float* hAl = lds;
      float* hBl = lds + 2048;
      for (int i = tid; i < 2048; i += 512) {
        hAl[i] = cLd(&A.h1d[nxt * 8192 + bq * 2048 + i]);
        hBl[i] = cLd(&A.h2d[cur * 8192 + bq * 2048 + i]);
      }
      __syncthreads();
      float acc[4][4] = {};
      for (int jj = 0; jj < 8; ++jj) {
        const int j = jj * 64 + sl;
        const float wa0 = A.c2Wih[(n) * 512 + j];
        const float wa1 = A.c2Wih[(512 + n) * 512 + j];
        const float wa2 = A.c2Wih[(1024 + n) * 512 + j];
        const float wa3 = A.c2Wih[(1536 + n) * 512 + j];
        const float wb0 = A.c2Whh[(n) * 512 + j];
        const float wb1 = A.c2Whh[(512 + n) * 512 + j];
        const float wb2 = A.c2Whh[(1024 + n) * 512 + j];
        const float wb3 = A.c2Whh[(1536 + n) * 512 + j];
#pragma unroll
        for (int bl = 0; bl < 4; ++bl) {
          const float ha = hAl[bl * 512 + j];
          const float hb = hBl[bl * 512 + j];
          acc[0][bl] += wa0 * ha + wb0 * hb;
          acc[1][bl] += wa1 * ha + wb1 * hb;
          acc[2][bl] += wa2 * ha + wb2 * hb;
          acc[3][bl] += wa3 * ha + wb3 * hb;
        }
      }
      red64(acc);
      if (sl == 0) {
#pragma unroll
        for (int bl = 0; bl < 4; ++bl) {
          const int b = bq * 4 + bl;
          const float gi = acc[0][bl] + A.c2bih[n] + A.c2bhh[n];
          const float gf = acc[1][bl] + A.c2bih[512 + n] + A.c2bhh[512 + n];
          const float gg = acc[2][bl] + A.c2bih[1024 + n] + A.c2bhh[1024 + n];
          const float go = acc[3][bl] + A.c2bih[1536 + n] + A.c2bhh[1536 + n];
          const float cp = cLd(&A.c2b[b * 512 + n]);
          const float cn = sigm(gf) * cp + sigm(gi) * tanhf(gg);
          const float hn = sigm(go) * tanhf(cn);
          cSt(&A.c2b[b * 512 + n], cn);
          cSt(&A.h2d[nxt * 8192 + b * 512 + n], hn);
        }
      }
    }
    gbar(A.flags, A.gen, bid, tid, bgen);
  }
}

// ---------------------------------------------------------------- launch
extern "C" void kernel_launch(void* const* d_in, const int* in_sizes, int n_in,
                              void* d_out, int out_size, void* d_ws, size_t ws_size,
                              hipStream_t stream) {
  (void)in_sizes; (void)n_in; (void)out_size; (void)ws_size;
  const float* window = (const float*)d_in[0];
  const int* ei = (const int*)d_in[1];
  const float* ew = (const float*)d_in[2];
  const float* Wemb = (const float*)d_in[3];
  const float* tgw = (const float*)d_in[4];
  const float* tgv = (const float*)d_in[5];
  const float* tgb = (const float*)d_in[6];
  const float* gw = (const float*)d_in[7];
  const float* gv = (const float*)d_in[8];
  const float* gb = (const float*)d_in[9];
  const float* Wih0 = (const float*)d_in[10];
  const float* Whh0 = (const float*)d_in[11];
  const float* bih0 = (const float*)d_in[12];
  const float* bhh0 = (const float*)d_in[13];
  const float* Wih1 = (const float*)d_in[14];
  const float* Whh1 = (const float*)d_in[15];
  const float* bih1 = (const float*)d_in[16];
  const float* bhh1 = (const float*)d_in[17];
  const float* c1Wih = (const float*)d_in[18];
  const float* c1Whh = (const float*)d_in[19];
  const float* c1bih = (const float*)d_in[20];
  const float* c1bhh = (const float*)d_in[21];
  const float* c2Wih = (const float*)d_in[22];
  const float* c2Whh = (const float*)d_in[23];
  const float* c2bih = (const float*)d_in[24];
  const float* c2bhh = (const float*)d_in[25];
  const float* Wp = (const float*)d_in[26];
  const float* bp = (const float*)d_in[27];

  char* w = (char*)d_ws;
  size_t off = 0;
  auto alloc = [&](size_t bytes) { void* p = w + off; off = (off + bytes + 255) & ~(size_t)255; return p; };
  int* cptr = (int*)alloc(101 * 4);
  int* csrc = (int*)alloc(2000 * 4);
  float* cnorm = (float*)alloc(2000 * 4);
  float* XS = (float*)alloc((size_t)1024 * 3200 * 4);
  float* G0 = (float*)alloc((size_t)1024 * 2048 * 4);
  float* hs0 = (float*)alloc((size_t)64 * 8192 * 4);
  float* hL1 = (float*)alloc((size_t)2 * 8192 * 4);
  float* c0 = (float*)alloc((size_t)8192 * 4);
  float* cL1 = (float*)alloc((size_t)8192 * 4);
  float* h1d = (float*)alloc((size_t)2 * 8192 * 4);
  float* c1b = (float*)alloc((size_t)8192 * 4);
  float* h2d = (float*)alloc((size_t)2 * 8192 * 4);
  float* c2b = (float*)alloc((size_t)8192 * 4);
  float* pred = (float*)alloc(1600 * 4);
  float* xin = (float*)alloc((size_t)51200 * 4);
  unsigned* flags = (unsigned*)alloc(NBLK * 4);
  unsigned* gen = (unsigned*)alloc(64);

  hipMemsetAsync(flags, 0, NBLK * 4, stream);
  hipMemsetAsync(gen, 0, 4, stream);

  setup_kernel<<<1, 256, 0, stream>>>(ei, ew, cptr, csrc, cnorm);
  xs_kernel<<<400, 256, 0, stream>>>(window, cptr, csrc, cnorm, tgw, tgv, tgb, Wemb, XS);
  g0_gemm<<<dim3(32, 16), 256, 0, stream>>>(XS, Wih0, bih0, bhh0, G0);

  CoopArgs A;
  A.G0 = G0; A.Whh0 = Whh0;
  A.Wih1 = Wih1; A.Whh1 = Whh1; A.bih1 = bih1; A.bhh1 = bhh1;
  A.c1Wih = c1Wih; A.c1Whh = c1Whh; A.c1bih = c1bih; A.c1bhh = c1bhh;
  A.c2Wih = c2Wih; A.c2Whh = c2Whh; A.c2bih = c2bih; A.c2bhh = c2bhh;
  A.Wp = Wp; A.bp = bp; A.gw = gw; A.gv = gv; A.gb = gb; A.Wemb = Wemb;
  A.cptr = cptr; A.csrc = csrc; A.cnorm = cnorm;
  A.hs0 = hs0; A.hL1 = hL1; A.c0 = c0; A.cL1 = cL1;
  A.h1d = h1d; A.c1b = c1b; A.h2d = h2d; A.c2b = c2b;
  A.pred = pred; A.xin = xin;
  A.flags = flags; A.gen = gen;
  A.out = (float*)d_out;
  void* params[] = { &A };
  hipLaunchCooperativeKernel(coop_kernel, dim3(NBLK), dim3(512), params, 0, stream);
}